// Round 9
// baseline (226.963 us; speedup 1.0000x reference)
//
#include <hip/hip_runtime.h>
#include <hip/hip_bf16.h>
#include <stdint.h>

typedef __bf16 bf16x8 __attribute__((ext_vector_type(8)));
typedef unsigned short ushort8 __attribute__((ext_vector_type(8)));
typedef unsigned short ushort4v __attribute__((ext_vector_type(4)));
typedef float f32x4 __attribute__((ext_vector_type(4)));
typedef unsigned int uint32x2 __attribute__((ext_vector_type(2)));
typedef unsigned int uint32x4 __attribute__((ext_vector_type(4)));

#define MFMA16(a, b, c) __builtin_amdgcn_mfma_f32_16x16x32_bf16((a), (b), (c), 0, 0, 0)

__device__ __forceinline__ unsigned short f2bf(float f) {
    uint32_t u = __float_as_uint(f);
    u += 0x7FFFu + ((u >> 16) & 1u);   // round-to-nearest-even
    return (unsigned short)(u >> 16);
}
__device__ __forceinline__ float bf2f(unsigned short u) {
    return __uint_as_float(((uint32_t)u) << 16);
}
// pack 2 f32 -> 2 bf16 (RNE) in one instr; bit-identical to f2bf pair.
__device__ __forceinline__ uint32_t pk_bf16(float lo, float hi) {
    uint32_t r;
    asm("v_cvt_pk_bf16_f32 %0, %1, %2" : "=v"(r) : "v"(lo), "v"(hi));
    return r;
}

// ------- kernel 1: pack Wt[640][512] = [W1|W2|W3]^T in bf16 (B-operand) ------
__global__ void k_build_wt(const float* __restrict__ W1, const float* __restrict__ W2,
                           const float* __restrict__ W3, unsigned short* __restrict__ Wt) {
    int idx = blockIdx.x * 256 + threadIdx.x;     // 0 .. 327679
    int n = idx >> 9;                              // output col 0..639
    int k = idx & 511;                             // input channel
    float v;
    if (n < 64)       v = W1[k * 64 + n];
    else if (n < 128) v = W2[k * 64 + (n - 64)];
    else              v = W3[k * 512 + (n - 128)];
    Wt[idx] = f2bf(v);
}

// -------- kernel 2: QKV projection GEMM, M=16384 K=512 N=640 (bf16 MFMA) -----
__global__ __launch_bounds__(512, 2) void k_proj(const float* __restrict__ x,
                                                 const unsigned short* __restrict__ Wt,
                                                 unsigned short* __restrict__ Qb,
                                                 unsigned short* __restrict__ Kb,
                                                 unsigned short* __restrict__ Vt) {
    __shared__ __align__(16) unsigned short As[64 * 520];
    const int tid  = threadIdx.x;
    const int lane = tid & 63;
    const int w    = tid >> 6;
    const int m0   = blockIdx.x * 64;
    const int col  = lane & 15, quad = lane >> 4;

    // stage A tile: 64 rows x 512 ch, convert fp32 -> bf16 (cvt_pk, RNE)
#pragma unroll
    for (int itr = 0; itr < 16; ++itr) {
        int idx = itr * 512 + tid;
        int row = idx >> 7, c4 = (idx & 127) << 2;
        f32x4 v = *(const f32x4*)(x + (m0 + row) * 512 + c4);
        uint32x2 o;
        o[0] = pk_bf16(v[0], v[1]); o[1] = pk_bf16(v[2], v[3]);
        *(uint32x2*)(&As[row * 520 + c4]) = o;
    }
    __syncthreads();

    f32x4 acc[4][5] = {};
    bf16x8 bcur[5], bnxt[5];
    const unsigned short* bp = Wt + quad * 8;
#pragma unroll
    for (int nt = 0; nt < 5; ++nt)
        bcur[nt] = *(const bf16x8*)(bp + (w * 80 + nt * 16 + col) * 512);

    for (int k = 0; k < 16; ++k) {
        int kn = (k + 1) & 15;                     // prefetch next k-step's B frags
#pragma unroll
        for (int nt = 0; nt < 5; ++nt)
            bnxt[nt] = *(const bf16x8*)(bp + (w * 80 + nt * 16 + col) * 512 + kn * 32);
        bf16x8 af[4];
#pragma unroll
        for (int it = 0; it < 4; ++it)
            af[it] = *(const bf16x8*)(&As[(it * 16 + col) * 520 + k * 32 + quad * 8]);
#pragma unroll
        for (int it = 0; it < 4; ++it)
#pragma unroll
            for (int nt = 0; nt < 5; ++nt)
                acc[it][nt] = MFMA16(af[it], bcur[nt], acc[it][nt]);
#pragma unroll
        for (int nt = 0; nt < 5; ++nt) bcur[nt] = bnxt[nt];
    }

#pragma unroll
    for (int nt = 0; nt < 5; ++nt) {
        int n0 = w * 80 + nt * 16;                 // wave-uniform
        if (n0 < 128) {                            // Q or K slab
            unsigned short* dst = (n0 < 64) ? Qb : Kb;
            int nc = (n0 < 64) ? (n0 + col) : (n0 - 64 + col);
#pragma unroll
            for (int it = 0; it < 4; ++it) {
                int ig = m0 + it * 16 + quad * 4;
#pragma unroll
                for (int r = 0; r < 4; ++r)
                    dst[(ig + r) * 64 + nc] = f2bf(acc[it][nt][r]);
            }
        } else {                                   // V slab -> transposed Vt[c][i]
            int vrow = n0 - 128 + col;
#pragma unroll
            for (int it = 0; it < 4; ++it) {
                int ig = m0 + it * 16 + quad * 4;
                int b = ig >> 12, ii = ig & 4095;
                uint32x2 pk;
                pk[0] = pk_bf16(acc[it][nt][0], acc[it][nt][1]);
                pk[1] = pk_bf16(acc[it][nt][2], acc[it][nt][3]);
                *(uint32x2*)(Vt + ((b * 512 + vrow) << 12) + ii) = pk;
            }
        }
    }
}

// ---------------- kernel 3: flash attention over a j-half, partial output ----
// R9 = R7 (verified 107.6us) + two LDS-instruction diets:
// (1) SWAPPED-OPERAND QK: MFMA16(kf, qf) computes D[key][qrow] with the SAME
//     operand fragment loads (A-row = lane&15 = key matches kf; B-col =
//     lane&15 = qrow matches qf). s[r] is then CONTIGUOUS in row-major Ss
//     (addr = (it*16+col)*132 + w*16 + quad*4 + r) -> one ds_write_b128 per
//     it instead of 4 scattered b32: 32 -> 8 write instrs/thread/jj.
//     Bank-check: word = 4*(33col+quad)+r -> every bank exactly 8 words.
//     Bit-identical (mult commutes; k-order unchanged).
// (2) al_s rescale read as one f32x4 per it (rb 16B-aligned): 32 -> 8.
// Everything else byte-identical to R7.
__global__ __launch_bounds__(512, 2) void k_flash(const unsigned short* __restrict__ Qb,
                                                  const unsigned short* __restrict__ Kb,
                                                  const unsigned short* __restrict__ Vt,
                                                  unsigned short* __restrict__ Op,
                                                  float* __restrict__ ml) {
    __shared__ __align__(16) unsigned short Qs[128 * 72];    // 18 KB
    __shared__ __align__(16) float          Ss[128 * 132];   // 67.5 KB
    __shared__ __align__(16) unsigned short Ps[128 * 136];   // 34.8 KB
    __shared__ float m_s[128], l_s[128], al_s[128];

    const int tid  = threadIdx.x;
    const int lane = tid & 63;
    const int w    = tid >> 6;
    const int col  = lane & 15, quad = lane >> 4;
    const int xcd  = blockIdx.x & 7;
    const int b    = xcd >> 1;
    const int jh   = xcd & 1;
    const int i0   = (blockIdx.x >> 3) * 128;

    const unsigned short* Qbase = Qb + (b * 4096 + i0) * 64;
    const unsigned short* Kbase = Kb + b * 4096 * 64;
    const unsigned short* Vbase = Vt + b * 512 * 4096;

    if (tid < 128) { m_s[tid] = -3.0e38f; l_s[tid] = 0.0f; }
    {   // stage Q tile: 128 rows x 64 ch, 16B per thread x 2
#pragma unroll
        for (int half = 0; half < 2; ++half) {
            int row = half * 64 + (tid >> 3), ch = tid & 7;
            *(ushort8*)(&Qs[row * 72 + ch * 8]) =
                *(const ushort8*)(Qbase + row * 64 + ch * 8);
        }
    }
    __syncthreads();

    f32x4 acc[8][4] = {};                          // 128 rows x 64 ch per wave

    for (int jj = 0; jj < 16; ++jj) {
        const int j0 = jh * 2048 + jj * 128;
        // ---- S = Q.K^T, swapped operands: D[key][qrow], vectorized S-write --
        {
            const unsigned short* kp = Kbase + (j0 + w * 16 + col) * 64 + quad * 8;
            bf16x8 kf0 = *(const bf16x8*)(kp);
            bf16x8 kf1 = *(const bf16x8*)(kp + 32);
#pragma unroll
            for (int it = 0; it < 8; ++it) {
                bf16x8 q0 = *(const bf16x8*)(&Qs[(it * 16 + col) * 72 + quad * 8]);
                bf16x8 q1 = *(const bf16x8*)(&Qs[(it * 16 + col) * 72 + 32 + quad * 8]);
                f32x4 s = {};
                s = MFMA16(kf0, q0, s);
                s = MFMA16(kf1, q1, s);
                // s[r] = S[it*16+col][j0 + w*16 + quad*4 + r] -> contiguous
                *(f32x4*)(&Ss[(it * 16 + col) * 132 + w * 16 + quad * 4]) = s;
            }
        }
        // V kk01 loads: issued here, latency hidden under barrier + softmax
        bf16x8 vf0[4][2];
#pragma unroll
        for (int ct = 0; ct < 4; ++ct) {
            const unsigned short* vp = Vbase + (w * 64 + ct * 16 + col) * 4096 + j0 + quad * 8;
            vf0[ct][0] = *(const bf16x8*)(vp);
            vf0[ct][1] = *(const bf16x8*)(vp + 32);
        }
        __syncthreads();
        // ---- online softmax: 4 threads per row, chunks g and g+4 ----
        {
            int row = tid >> 2, g = tid & 3;
            float* spA = &Ss[row * 132 + g * 16];
            float* spB = &Ss[row * 132 + (g + 4) * 16];
            f32x4 v0 = *(f32x4*)(spA + 0);
            f32x4 v1 = *(f32x4*)(spA + 4);
            f32x4 v2 = *(f32x4*)(spA + 8);
            f32x4 v3 = *(f32x4*)(spA + 12);
            f32x4 u0 = *(f32x4*)(spB + 0);
            f32x4 u1 = *(f32x4*)(spB + 4);
            f32x4 u2 = *(f32x4*)(spB + 8);
            f32x4 u3 = *(f32x4*)(spB + 12);
            float mx = fmaxf(fmaxf(fmaxf(v0[0], v0[1]), fmaxf(v0[2], v0[3])),
                             fmaxf(fmaxf(v1[0], v1[1]), fmaxf(v1[2], v1[3])));
            mx = fmaxf(mx, fmaxf(fmaxf(fmaxf(v2[0], v2[1]), fmaxf(v2[2], v2[3])),
                                 fmaxf(fmaxf(v3[0], v3[1]), fmaxf(v3[2], v3[3]))));
            mx = fmaxf(mx, fmaxf(fmaxf(fmaxf(u0[0], u0[1]), fmaxf(u0[2], u0[3])),
                                 fmaxf(fmaxf(u1[0], u1[1]), fmaxf(u1[2], u1[3]))));
            mx = fmaxf(mx, fmaxf(fmaxf(fmaxf(u2[0], u2[1]), fmaxf(u2[2], u2[3])),
                                 fmaxf(fmaxf(u3[0], u3[1]), fmaxf(u3[2], u3[3]))));
            mx = fmaxf(mx, __shfl_xor(mx, 1, 4));
            mx = fmaxf(mx, __shfl_xor(mx, 2, 4));
            float mo = m_s[row];
            float mn = fmaxf(mo, mx);
            float al = __expf(mo - mn);
#pragma unroll
            for (int i = 0; i < 4; ++i) {
                v0[i] = __expf(v0[i] - mn); v1[i] = __expf(v1[i] - mn);
                v2[i] = __expf(v2[i] - mn); v3[i] = __expf(v3[i] - mn);
                u0[i] = __expf(u0[i] - mn); u1[i] = __expf(u1[i] - mn);
                u2[i] = __expf(u2[i] - mn); u3[i] = __expf(u3[i] - mn);
            }
            float sum = (v0[0]+v0[1]+v0[2]+v0[3]) + (v1[0]+v1[1]+v1[2]+v1[3])
                      + (v2[0]+v2[1]+v2[2]+v2[3]) + (v3[0]+v3[1]+v3[2]+v3[3])
                      + (u0[0]+u0[1]+u0[2]+u0[3]) + (u1[0]+u1[1]+u1[2]+u1[3])
                      + (u2[0]+u2[1]+u2[2]+u2[3]) + (u3[0]+u3[1]+u3[2]+u3[3]);
            // pack P to bf16 via cvt_pk (bit-identical RNE)
            uint32x4 w0, w1;
            w0[0] = pk_bf16(v0[0], v0[1]); w0[1] = pk_bf16(v0[2], v0[3]);
            w0[2] = pk_bf16(v1[0], v1[1]); w0[3] = pk_bf16(v1[2], v1[3]);
            w1[0] = pk_bf16(v2[0], v2[1]); w1[1] = pk_bf16(v2[2], v2[3]);
            w1[2] = pk_bf16(v3[0], v3[1]); w1[3] = pk_bf16(v3[2], v3[3]);
            *(uint32x4*)(&Ps[row * 136 + g * 16])     = w0;
            *(uint32x4*)(&Ps[row * 136 + g * 16 + 8]) = w1;
            uint32x4 w2, w3;
            w2[0] = pk_bf16(u0[0], u0[1]); w2[1] = pk_bf16(u0[2], u0[3]);
            w2[2] = pk_bf16(u1[0], u1[1]); w2[3] = pk_bf16(u1[2], u1[3]);
            w3[0] = pk_bf16(u2[0], u2[1]); w3[1] = pk_bf16(u2[2], u2[3]);
            w3[2] = pk_bf16(u3[0], u3[1]); w3[3] = pk_bf16(u3[2], u3[3]);
            *(uint32x4*)(&Ps[row * 136 + (g + 4) * 16])     = w2;
            *(uint32x4*)(&Ps[row * 136 + (g + 4) * 16 + 8]) = w3;
            sum += __shfl_xor(sum, 1, 4);
            sum += __shfl_xor(sum, 2, 4);
            if (g == 0) { m_s[row] = mn; l_s[row] = al * l_s[row] + sum; al_s[row] = al; }
        }
        __syncthreads();
        // ---- rescale O (vectorized al reads) ----
#pragma unroll
        for (int it = 0; it < 8; ++it) {
            int rb = it * 16 + quad * 4;
            f32x4 av = *(const f32x4*)(&al_s[rb]);
#pragma unroll
            for (int ct = 0; ct < 4; ++ct) acc[it][ct] *= av;
        }
        // ---- PV kk = 0,1 (vf0 in flight since before the barrier) ----
        __builtin_amdgcn_s_setprio(1);
#pragma unroll
        for (int it = 0; it < 8; ++it) {
            bf16x8 pf0 = *(const bf16x8*)(&Ps[(it * 16 + col) * 136 + quad * 8]);
            bf16x8 pf1 = *(const bf16x8*)(&Ps[(it * 16 + col) * 136 + 32 + quad * 8]);
#pragma unroll
            for (int ct = 0; ct < 4; ++ct) {
                acc[it][ct] = MFMA16(pf0, vf0[ct][0], acc[it][ct]);
                acc[it][ct] = MFMA16(pf1, vf0[ct][1], acc[it][ct]);
            }
        }
        __builtin_amdgcn_s_setprio(0);
        // ---- V kk = 2,3 loads + PV ----
        bf16x8 vf1[4][2];
#pragma unroll
        for (int ct = 0; ct < 4; ++ct) {
            const unsigned short* vp = Vbase + (w * 64 + ct * 16 + col) * 4096 + j0 + quad * 8;
            vf1[ct][0] = *(const bf16x8*)(vp + 64);
            vf1[ct][1] = *(const bf16x8*)(vp + 96);
        }
        __builtin_amdgcn_s_setprio(1);
#pragma unroll
        for (int it = 0; it < 8; ++it) {
            bf16x8 pf2 = *(const bf16x8*)(&Ps[(it * 16 + col) * 136 + 64 + quad * 8]);
            bf16x8 pf3 = *(const bf16x8*)(&Ps[(it * 16 + col) * 136 + 96 + quad * 8]);
#pragma unroll
            for (int ct = 0; ct < 4; ++ct) {
                acc[it][ct] = MFMA16(pf2, vf1[ct][0], acc[it][ct]);
                acc[it][ct] = MFMA16(pf3, vf1[ct][1], acc[it][ct]);
            }
        }
        __builtin_amdgcn_s_setprio(0);
    }

    // ---- epilogue: store unnormalized partial O (bf16) + (m,l) per row ----
    unsigned short* obh = Op + jh * 8388608 + b * 2097152;
#pragma unroll
    for (int it = 0; it < 8; ++it) {
        int rb = it * 16 + quad * 4;
#pragma unroll
        for (int ct = 0; ct < 4; ++ct) {
            int cg = w * 64 + ct * 16 + col;
            int f = cg * 4096 + i0 + rb;
            uint32x2 pk;
            f32x4 a = acc[it][ct];
            pk[0] = pk_bf16(a[0], a[1]); pk[1] = pk_bf16(a[2], a[3]);
            *(uint32x2*)(obh + f) = pk;
        }
    }
    if (tid < 128) {
        float2 v; v.x = m_s[tid]; v.y = l_s[tid];
        ((float2*)ml)[(jh * 4 + b) * 4096 + i0 + tid] = v;
    }
}

// ------------- kernel 4: per-row combine weights c0,c1 (folds gamma) --------
__global__ void k_mlw(const float* __restrict__ ml, const float* __restrict__ gamma,
                      float* __restrict__ cw) {
    int t = blockIdx.x * 256 + threadIdx.x;        // 16384 rows (b,i)
    float2 a = ((const float2*)ml)[t];             // jh = 0 : (m0, l0)
    float2 c = ((const float2*)ml)[16384 + t];     // jh = 1 : (m1, l1)
    float M = fmaxf(a.x, c.x);
    float e0 = __expf(a.x - M), e1 = __expf(c.x - M);
    float g = gamma[0] / (e0 * a.y + e1 * c.y);
    float2 o; o.x = g * e0; o.y = g * e1;
    ((float2*)cw)[t] = o;
}

// ------------- kernel 5: combine halves + residual (memory-bound) -----------
__global__ void k_combine(const unsigned short* __restrict__ Op,
                          const float* __restrict__ cw,
                          const float* __restrict__ x, float* __restrict__ out) {
    int t = blockIdx.x * 256 + threadIdx.x;        // 0 .. 2097151
    int f = t << 2;                                // flat float index into out
    int b = f >> 21, i = f & 4095;                 // i = attention row (raw reshape)
    const float* cwf = cw + (((b << 12) + i) << 1);
    f32x4 wa = *(const f32x4*)(cwf);               // c0_i, c1_i, c0_i1, c1_i1
    f32x4 wb = *(const f32x4*)(cwf + 4);
    ushort4v o0 = *(const ushort4v*)(Op + f);
    ushort4v o1 = *(const ushort4v*)(Op + 8388608 + f);
    f32x4 xv = *(const f32x4*)(x + f);
    f32x4 o;
    o[0] = wa[0] * bf2f(o0[0]) + wa[1] * bf2f(o1[0]) + xv[0];
    o[1] = wa[2] * bf2f(o0[1]) + wa[3] * bf2f(o1[1]) + xv[1];
    o[2] = wb[0] * bf2f(o0[2]) + wb[1] * bf2f(o1[2]) + xv[2];
    o[3] = wb[2] * bf2f(o0[3]) + wb[3] * bf2f(o1[3]) + xv[3];
    *(f32x4*)(out + f) = o;
}

extern "C" void kernel_launch(void* const* d_in, const int* in_sizes, int n_in,
                              void* d_out, int out_size, void* d_ws, size_t ws_size,
                              hipStream_t stream) {
    const float* x  = (const float*)d_in[0];
    const float* W1 = (const float*)d_in[1];
    const float* W2 = (const float*)d_in[2];
    const float* W3 = (const float*)d_in[3];
    const float* gm = (const float*)d_in[4];
    float* out = (float*)d_out;

    char* ws = (char*)d_ws;
    unsigned short* Wt = (unsigned short*)(ws);                    // 640 KiB @ 0
    unsigned short* Qb = (unsigned short*)(ws + (1u  << 20));      // 2 MiB
    unsigned short* Kb = (unsigned short*)(ws + (3u  << 20));      // 2 MiB
    unsigned short* Vt = (unsigned short*)(ws + (5u  << 20));      // 16 MiB
    unsigned short* Op = (unsigned short*)(ws + (21u << 20));      // 32 MiB (2 halves)
    float*          ml = (float*)        (ws + (53u << 20));       // 256 KiB
    float*          cw = (float*)        (ws + (53u << 20) + 262144); // 128 KiB

    hipLaunchKernelGGL(k_build_wt, dim3(1280), dim3(256), 0, stream, W1, W2, W3, Wt);
    hipLaunchKernelGGL(k_proj,     dim3(256),  dim3(512), 0, stream, x, Wt, Qb, Kb, Vt);
    hipLaunchKernelGGL(k_flash,    dim3(256),  dim3(512), 0, stream, Qb, Kb, Vt, Op, ml);
    hipLaunchKernelGGL(k_mlw,      dim3(64),   dim3(256), 0, stream, ml, gm, cw);
    hipLaunchKernelGGL(k_combine,  dim3(8192), dim3(256), 0, stream, Op, cw, x, out);
}

// Round 10
// 217.748 us; speedup vs baseline: 1.0423x; 1.0423x over previous
//
#include <hip/hip_runtime.h>
#include <hip/hip_bf16.h>
#include <stdint.h>

typedef __bf16 bf16x8 __attribute__((ext_vector_type(8)));
typedef unsigned short ushort8 __attribute__((ext_vector_type(8)));
typedef unsigned short ushort4v __attribute__((ext_vector_type(4)));
typedef float f32x4 __attribute__((ext_vector_type(4)));
typedef unsigned int uint32x2 __attribute__((ext_vector_type(2)));
typedef unsigned int uint32x4 __attribute__((ext_vector_type(4)));

#define MFMA16(a, b, c) __builtin_amdgcn_mfma_f32_16x16x32_bf16((a), (b), (c), 0, 0, 0)

__device__ __forceinline__ unsigned short f2bf(float f) {
    uint32_t u = __float_as_uint(f);
    u += 0x7FFFu + ((u >> 16) & 1u);   // round-to-nearest-even
    return (unsigned short)(u >> 16);
}
__device__ __forceinline__ float bf2f(unsigned short u) {
    return __uint_as_float(((uint32_t)u) << 16);
}
// pack 2 f32 -> 2 bf16 (RNE) in one instr; bit-identical to f2bf pair.
__device__ __forceinline__ uint32_t pk_bf16(float lo, float hi) {
    uint32_t r;
    asm("v_cvt_pk_bf16_f32 %0, %1, %2" : "=v"(r) : "v"(lo), "v"(hi));
    return r;
}

// ------- kernel 1: pack Wt[640][512] = [W1|W2|W3]^T in bf16 (B-operand) ------
__global__ void k_build_wt(const float* __restrict__ W1, const float* __restrict__ W2,
                           const float* __restrict__ W3, unsigned short* __restrict__ Wt) {
    int idx = blockIdx.x * 256 + threadIdx.x;     // 0 .. 327679
    int n = idx >> 9;                              // output col 0..639
    int k = idx & 511;                             // input channel
    float v;
    if (n < 64)       v = W1[k * 64 + n];
    else if (n < 128) v = W2[k * 64 + (n - 64)];
    else              v = W3[k * 512 + (n - 128)];
    Wt[idx] = f2bf(v);
}

// -------- kernel 2: QKV projection GEMM, M=16384 K=512 N=640 (bf16 MFMA) -----
// R10: V-slab epilogue now goes through LDS (reusing the A-staging buffer,
// padded to [512 ch][72 rows]) so the 16 MB of Vt writes leave as fully
// coalesced 128B lines instead of 8B chunks at 8 KB stride (which cost up to
// 8x write-sector amplification). Write side <=2-way bank aliased (free);
// read side ds_read_b128 at word 36c+4(tid&7), 16B-aligned, bank-minimal.
// Values bit-identical (same pk_bf16).
__global__ __launch_bounds__(512, 2) void k_proj(const float* __restrict__ x,
                                                 const unsigned short* __restrict__ Wt,
                                                 unsigned short* __restrict__ Qb,
                                                 unsigned short* __restrict__ Kb,
                                                 unsigned short* __restrict__ Vt) {
    __shared__ __align__(16) unsigned short As[512 * 72];   // 72 KB; staging view = [64][520]
    const int tid  = threadIdx.x;
    const int lane = tid & 63;
    const int w    = tid >> 6;
    const int m0   = blockIdx.x * 64;
    const int col  = lane & 15, quad = lane >> 4;

    // stage A tile: 64 rows x 512 ch, convert fp32 -> bf16 (cvt_pk, RNE)
#pragma unroll
    for (int itr = 0; itr < 16; ++itr) {
        int idx = itr * 512 + tid;
        int row = idx >> 7, c4 = (idx & 127) << 2;
        f32x4 v = *(const f32x4*)(x + (m0 + row) * 512 + c4);
        uint32x2 o;
        o[0] = pk_bf16(v[0], v[1]); o[1] = pk_bf16(v[2], v[3]);
        *(uint32x2*)(&As[row * 520 + c4]) = o;
    }
    __syncthreads();

    f32x4 acc[4][5] = {};
    bf16x8 bcur[5], bnxt[5];
    const unsigned short* bp = Wt + quad * 8;
#pragma unroll
    for (int nt = 0; nt < 5; ++nt)
        bcur[nt] = *(const bf16x8*)(bp + (w * 80 + nt * 16 + col) * 512);

    for (int k = 0; k < 16; ++k) {
        int kn = (k + 1) & 15;                     // prefetch next k-step's B frags
#pragma unroll
        for (int nt = 0; nt < 5; ++nt)
            bnxt[nt] = *(const bf16x8*)(bp + (w * 80 + nt * 16 + col) * 512 + kn * 32);
        bf16x8 af[4];
#pragma unroll
        for (int it = 0; it < 4; ++it)
            af[it] = *(const bf16x8*)(&As[(it * 16 + col) * 520 + k * 32 + quad * 8]);
#pragma unroll
        for (int it = 0; it < 4; ++it)
#pragma unroll
            for (int nt = 0; nt < 5; ++nt)
                acc[it][nt] = MFMA16(af[it], bcur[nt], acc[it][nt]);
#pragma unroll
        for (int nt = 0; nt < 5; ++nt) bcur[nt] = bnxt[nt];
    }

    __syncthreads();   // all As staging reads complete before V reuses it

#pragma unroll
    for (int nt = 0; nt < 5; ++nt) {
        int n0 = w * 80 + nt * 16;                 // wave-uniform
        if (n0 < 128) {                            // Q or K slab: direct store
            unsigned short* dst = (n0 < 64) ? Qb : Kb;
            int nc = (n0 < 64) ? (n0 + col) : (n0 - 64 + col);
#pragma unroll
            for (int it = 0; it < 4; ++it) {
                int ig = m0 + it * 16 + quad * 4;
#pragma unroll
                for (int r = 0; r < 4; ++r)
                    dst[(ig + r) * 64 + nc] = f2bf(acc[it][nt][r]);
            }
        } else {                                   // V slab -> LDS [ch][row]
            int vrow = n0 - 128 + col;             // 0..511
#pragma unroll
            for (int it = 0; it < 4; ++it) {
                int rowoff = it * 16 + quad * 4;
                uint32x2 pk;
                pk[0] = pk_bf16(acc[it][nt][0], acc[it][nt][1]);
                pk[1] = pk_bf16(acc[it][nt][2], acc[it][nt][3]);
                *(uint32x2*)(&As[vrow * 72 + rowoff]) = pk;
            }
        }
    }
    __syncthreads();
    // coalesced copy-out: 512 ch x 64 rows x 2B = 64 KB; 16B/thread x 8 iters.
    {
        const int bb = m0 >> 12;
        const int ibase = m0 & 4095;
        unsigned short* vdst = Vt + (((unsigned)(bb * 512)) << 12) + ibase;
#pragma unroll
        for (int itr = 0; itr < 8; ++itr) {
            int g = itr * 4096 + tid * 8;
            int c = g >> 6;                        // channel
            int row = g & 63;                      // row%8 == 0
            ushort8 vv = *(const ushort8*)(&As[c * 72 + row]);
            *(ushort8*)(vdst + (c << 12) + row) = vv;
        }
    }
}

// ---------------- kernel 3: flash attention over a j-half, partial output ----
// R7 VERBATIM (verified 107.6 us; R8's 32x32 and R9's swapped-QK both
// regressed ~7% -- this phase structure is a sharp local optimum).
__global__ __launch_bounds__(512, 2) void k_flash(const unsigned short* __restrict__ Qb,
                                                  const unsigned short* __restrict__ Kb,
                                                  const unsigned short* __restrict__ Vt,
                                                  unsigned short* __restrict__ Op,
                                                  float* __restrict__ ml) {
    __shared__ __align__(16) unsigned short Qs[128 * 72];    // 18 KB
    __shared__ __align__(16) float          Ss[128 * 132];   // 67.5 KB
    __shared__ __align__(16) unsigned short Ps[128 * 136];   // 34.8 KB
    __shared__ float m_s[128], l_s[128], al_s[128];

    const int tid  = threadIdx.x;
    const int lane = tid & 63;
    const int w    = tid >> 6;
    const int col  = lane & 15, quad = lane >> 4;
    const int xcd  = blockIdx.x & 7;
    const int b    = xcd >> 1;
    const int jh   = xcd & 1;
    const int i0   = (blockIdx.x >> 3) * 128;

    const unsigned short* Qbase = Qb + (b * 4096 + i0) * 64;
    const unsigned short* Kbase = Kb + b * 4096 * 64;
    const unsigned short* Vbase = Vt + b * 512 * 4096;

    if (tid < 128) { m_s[tid] = -3.0e38f; l_s[tid] = 0.0f; }
    {   // stage Q tile: 128 rows x 64 ch, 16B per thread x 2
#pragma unroll
        for (int half = 0; half < 2; ++half) {
            int row = half * 64 + (tid >> 3), ch = tid & 7;
            *(ushort8*)(&Qs[row * 72 + ch * 8]) =
                *(const ushort8*)(Qbase + row * 64 + ch * 8);
        }
    }
    __syncthreads();

    f32x4 acc[8][4] = {};                          // 128 rows x 64 ch per wave

    for (int jj = 0; jj < 16; ++jj) {
        const int j0 = jh * 2048 + jj * 128;
        // ---- S = Q.K^T : wave w computes score cols [j0+16w, j0+16w+16) ----
        {
            const unsigned short* kp = Kbase + (j0 + w * 16 + col) * 64 + quad * 8;
            bf16x8 kf0 = *(const bf16x8*)(kp);
            bf16x8 kf1 = *(const bf16x8*)(kp + 32);
#pragma unroll
            for (int it = 0; it < 8; ++it) {
                bf16x8 q0 = *(const bf16x8*)(&Qs[(it * 16 + col) * 72 + quad * 8]);
                bf16x8 q1 = *(const bf16x8*)(&Qs[(it * 16 + col) * 72 + 32 + quad * 8]);
                f32x4 s = {};
                s = MFMA16(q0, kf0, s);
                s = MFMA16(q1, kf1, s);
                int rb = it * 16 + quad * 4;
#pragma unroll
                for (int r = 0; r < 4; ++r) Ss[(rb + r) * 132 + w * 16 + col] = s[r];
            }
        }
        // V kk01 loads: issued here, latency hidden under barrier + softmax
        bf16x8 vf0[4][2];
#pragma unroll
        for (int ct = 0; ct < 4; ++ct) {
            const unsigned short* vp = Vbase + (w * 64 + ct * 16 + col) * 4096 + j0 + quad * 8;
            vf0[ct][0] = *(const bf16x8*)(vp);
            vf0[ct][1] = *(const bf16x8*)(vp + 32);
        }
        __syncthreads();
        // ---- online softmax: 4 threads per row, chunks g and g+4 ----
        {
            int row = tid >> 2, g = tid & 3;
            float* spA = &Ss[row * 132 + g * 16];
            float* spB = &Ss[row * 132 + (g + 4) * 16];
            f32x4 v0 = *(f32x4*)(spA + 0);
            f32x4 v1 = *(f32x4*)(spA + 4);
            f32x4 v2 = *(f32x4*)(spA + 8);
            f32x4 v3 = *(f32x4*)(spA + 12);
            f32x4 u0 = *(f32x4*)(spB + 0);
            f32x4 u1 = *(f32x4*)(spB + 4);
            f32x4 u2 = *(f32x4*)(spB + 8);
            f32x4 u3 = *(f32x4*)(spB + 12);
            float mx = fmaxf(fmaxf(fmaxf(v0[0], v0[1]), fmaxf(v0[2], v0[3])),
                             fmaxf(fmaxf(v1[0], v1[1]), fmaxf(v1[2], v1[3])));
            mx = fmaxf(mx, fmaxf(fmaxf(fmaxf(v2[0], v2[1]), fmaxf(v2[2], v2[3])),
                                 fmaxf(fmaxf(v3[0], v3[1]), fmaxf(v3[2], v3[3]))));
            mx = fmaxf(mx, fmaxf(fmaxf(fmaxf(u0[0], u0[1]), fmaxf(u0[2], u0[3])),
                                 fmaxf(fmaxf(u1[0], u1[1]), fmaxf(u1[2], u1[3]))));
            mx = fmaxf(mx, fmaxf(fmaxf(fmaxf(u2[0], u2[1]), fmaxf(u2[2], u2[3])),
                                 fmaxf(fmaxf(u3[0], u3[1]), fmaxf(u3[2], u3[3]))));
            mx = fmaxf(mx, __shfl_xor(mx, 1, 4));
            mx = fmaxf(mx, __shfl_xor(mx, 2, 4));
            float mo = m_s[row];
            float mn = fmaxf(mo, mx);
            float al = __expf(mo - mn);
#pragma unroll
            for (int i = 0; i < 4; ++i) {
                v0[i] = __expf(v0[i] - mn); v1[i] = __expf(v1[i] - mn);
                v2[i] = __expf(v2[i] - mn); v3[i] = __expf(v3[i] - mn);
                u0[i] = __expf(u0[i] - mn); u1[i] = __expf(u1[i] - mn);
                u2[i] = __expf(u2[i] - mn); u3[i] = __expf(u3[i] - mn);
            }
            float sum = (v0[0]+v0[1]+v0[2]+v0[3]) + (v1[0]+v1[1]+v1[2]+v1[3])
                      + (v2[0]+v2[1]+v2[2]+v2[3]) + (v3[0]+v3[1]+v3[2]+v3[3])
                      + (u0[0]+u0[1]+u0[2]+u0[3]) + (u1[0]+u1[1]+u1[2]+u1[3])
                      + (u2[0]+u2[1]+u2[2]+u2[3]) + (u3[0]+u3[1]+u3[2]+u3[3]);
            // pack P to bf16 via cvt_pk (bit-identical RNE)
            uint32x4 w0, w1;
            w0[0] = pk_bf16(v0[0], v0[1]); w0[1] = pk_bf16(v0[2], v0[3]);
            w0[2] = pk_bf16(v1[0], v1[1]); w0[3] = pk_bf16(v1[2], v1[3]);
            w1[0] = pk_bf16(v2[0], v2[1]); w1[1] = pk_bf16(v2[2], v2[3]);
            w1[2] = pk_bf16(v3[0], v3[1]); w1[3] = pk_bf16(v3[2], v3[3]);
            *(uint32x4*)(&Ps[row * 136 + g * 16])     = w0;
            *(uint32x4*)(&Ps[row * 136 + g * 16 + 8]) = w1;
            uint32x4 w2, w3;
            w2[0] = pk_bf16(u0[0], u0[1]); w2[1] = pk_bf16(u0[2], u0[3]);
            w2[2] = pk_bf16(u1[0], u1[1]); w2[3] = pk_bf16(u1[2], u1[3]);
            w3[0] = pk_bf16(u2[0], u2[1]); w3[1] = pk_bf16(u2[2], u2[3]);
            w3[2] = pk_bf16(u3[0], u3[1]); w3[3] = pk_bf16(u3[2], u3[3]);
            *(uint32x4*)(&Ps[row * 136 + (g + 4) * 16])     = w2;
            *(uint32x4*)(&Ps[row * 136 + (g + 4) * 16 + 8]) = w3;
            sum += __shfl_xor(sum, 1, 4);
            sum += __shfl_xor(sum, 2, 4);
            if (g == 0) { m_s[row] = mn; l_s[row] = al * l_s[row] + sum; al_s[row] = al; }
        }
        __syncthreads();
        // ---- rescale O ----
#pragma unroll
        for (int it = 0; it < 8; ++it) {
            int rb = it * 16 + quad * 4;
            f32x4 av;
            av[0] = al_s[rb]; av[1] = al_s[rb + 1]; av[2] = al_s[rb + 2]; av[3] = al_s[rb + 3];
#pragma unroll
            for (int ct = 0; ct < 4; ++ct) acc[it][ct] *= av;
        }
        // ---- PV kk = 0,1 (vf0 in flight since before the barrier) ----
        __builtin_amdgcn_s_setprio(1);
#pragma unroll
        for (int it = 0; it < 8; ++it) {
            bf16x8 pf0 = *(const bf16x8*)(&Ps[(it * 16 + col) * 136 + quad * 8]);
            bf16x8 pf1 = *(const bf16x8*)(&Ps[(it * 16 + col) * 136 + 32 + quad * 8]);
#pragma unroll
            for (int ct = 0; ct < 4; ++ct) {
                acc[it][ct] = MFMA16(pf0, vf0[ct][0], acc[it][ct]);
                acc[it][ct] = MFMA16(pf1, vf0[ct][1], acc[it][ct]);
            }
        }
        __builtin_amdgcn_s_setprio(0);
        // ---- V kk = 2,3 loads + PV ----
        bf16x8 vf1[4][2];
#pragma unroll
        for (int ct = 0; ct < 4; ++ct) {
            const unsigned short* vp = Vbase + (w * 64 + ct * 16 + col) * 4096 + j0 + quad * 8;
            vf1[ct][0] = *(const bf16x8*)(vp + 64);
            vf1[ct][1] = *(const bf16x8*)(vp + 96);
        }
        __builtin_amdgcn_s_setprio(1);
#pragma unroll
        for (int it = 0; it < 8; ++it) {
            bf16x8 pf2 = *(const bf16x8*)(&Ps[(it * 16 + col) * 136 + 64 + quad * 8]);
            bf16x8 pf3 = *(const bf16x8*)(&Ps[(it * 16 + col) * 136 + 96 + quad * 8]);
#pragma unroll
            for (int ct = 0; ct < 4; ++ct) {
                acc[it][ct] = MFMA16(pf2, vf1[ct][0], acc[it][ct]);
                acc[it][ct] = MFMA16(pf3, vf1[ct][1], acc[it][ct]);
            }
        }
        __builtin_amdgcn_s_setprio(0);
    }

    // ---- epilogue: store unnormalized partial O (bf16) + (m,l) per row ----
    unsigned short* obh = Op + jh * 8388608 + b * 2097152;
#pragma unroll
    for (int it = 0; it < 8; ++it) {
        int rb = it * 16 + quad * 4;
#pragma unroll
        for (int ct = 0; ct < 4; ++ct) {
            int cg = w * 64 + ct * 16 + col;
            int f = cg * 4096 + i0 + rb;
            uint32x2 pk;
            f32x4 a = acc[it][ct];
            pk[0] = pk_bf16(a[0], a[1]); pk[1] = pk_bf16(a[2], a[3]);
            *(uint32x2*)(obh + f) = pk;
        }
    }
    if (tid < 128) {
        float2 v; v.x = m_s[tid]; v.y = l_s[tid];
        ((float2*)ml)[(jh * 4 + b) * 4096 + i0 + tid] = v;
    }
}

// ------ kernel 4: combine halves + residual, with fused per-row weights -----
// (k_mlw folded in: identical FP expression order per row -> bit-identical.)
__global__ void k_combine(const unsigned short* __restrict__ Op,
                          const float* __restrict__ ml,
                          const float* __restrict__ gamma,
                          const float* __restrict__ x, float* __restrict__ out) {
    int t = blockIdx.x * 256 + threadIdx.x;        // 0 .. 2097151
    int f = t << 2;                                // flat float index into out
    int b = f >> 21, i = f & 4095;                 // i = attention row (raw reshape)
    const float* m0p = ml + (b * 4096 + i) * 2;          // jh=0 (m,l) rows i..i+3
    const float* m1p = ml + ((4 + b) * 4096 + i) * 2;    // jh=1
    f32x4 a0 = *(const f32x4*)(m0p);               // m0_i, l0_i, m0_i1, l0_i1
    f32x4 a1 = *(const f32x4*)(m0p + 4);           // rows i+2, i+3
    f32x4 c0 = *(const f32x4*)(m1p);
    f32x4 c1 = *(const f32x4*)(m1p + 4);
    float gm = gamma[0];
    f32x4 wa, wb;
    {   float M = fmaxf(a0[0], c0[0]);
        float e0 = __expf(a0[0] - M), e1 = __expf(c0[0] - M);
        float g = gm / (e0 * a0[1] + e1 * c0[1]);
        wa[0] = g * e0; wa[1] = g * e1; }
    {   float M = fmaxf(a0[2], c0[2]);
        float e0 = __expf(a0[2] - M), e1 = __expf(c0[2] - M);
        float g = gm / (e0 * a0[3] + e1 * c0[3]);
        wa[2] = g * e0; wa[3] = g * e1; }
    {   float M = fmaxf(a1[0], c1[0]);
        float e0 = __expf(a1[0] - M), e1 = __expf(c1[0] - M);
        float g = gm / (e0 * a1[1] + e1 * c1[1]);
        wb[0] = g * e0; wb[1] = g * e1; }
    {   float M = fmaxf(a1[2], c1[2]);
        float e0 = __expf(a1[2] - M), e1 = __expf(c1[2] - M);
        float g = gm / (e0 * a1[3] + e1 * c1[3]);
        wb[2] = g * e0; wb[3] = g * e1; }
    ushort4v o0 = *(const ushort4v*)(Op + f);
    ushort4v o1 = *(const ushort4v*)(Op + 8388608 + f);
    f32x4 xv = *(const f32x4*)(x + f);
    f32x4 o;
    o[0] = wa[0] * bf2f(o0[0]) + wa[1] * bf2f(o1[0]) + xv[0];
    o[1] = wa[2] * bf2f(o0[1]) + wa[3] * bf2f(o1[1]) + xv[1];
    o[2] = wb[0] * bf2f(o0[2]) + wb[1] * bf2f(o1[2]) + xv[2];
    o[3] = wb[2] * bf2f(o0[3]) + wb[3] * bf2f(o1[3]) + xv[3];
    *(f32x4*)(out + f) = o;
}

extern "C" void kernel_launch(void* const* d_in, const int* in_sizes, int n_in,
                              void* d_out, int out_size, void* d_ws, size_t ws_size,
                              hipStream_t stream) {
    const float* x  = (const float*)d_in[0];
    const float* W1 = (const float*)d_in[1];
    const float* W2 = (const float*)d_in[2];
    const float* W3 = (const float*)d_in[3];
    const float* gm = (const float*)d_in[4];
    float* out = (float*)d_out;

    char* ws = (char*)d_ws;
    unsigned short* Wt = (unsigned short*)(ws);                    // 640 KiB @ 0
    unsigned short* Qb = (unsigned short*)(ws + (1u  << 20));      // 2 MiB
    unsigned short* Kb = (unsigned short*)(ws + (3u  << 20));      // 2 MiB
    unsigned short* Vt = (unsigned short*)(ws + (5u  << 20));      // 16 MiB
    unsigned short* Op = (unsigned short*)(ws + (21u << 20));      // 32 MiB (2 halves)
    float*          ml = (float*)        (ws + (53u << 20));       // 256 KiB

    hipLaunchKernelGGL(k_build_wt, dim3(1280), dim3(256), 0, stream, W1, W2, W3, Wt);
    hipLaunchKernelGGL(k_proj,     dim3(256),  dim3(512), 0, stream, x, Wt, Qb, Kb, Vt);
    hipLaunchKernelGGL(k_flash,    dim3(256),  dim3(512), 0, stream, Qb, Kb, Vt, Op, ml);
    hipLaunchKernelGGL(k_combine,  dim3(8192), dim3(256), 0, stream, Op, ml, gm, x, out);
}